// Round 3
// baseline (1548.691 us; speedup 1.0000x reference)
//
#include <hip/hip_runtime.h>
#include <cmath>

#define N_PTS 200000
#define HD 64
#define CD 128
#define KEEP 63

typedef __bf16 bf16;
typedef __bf16 bf16x4 __attribute__((ext_vector_type(4)));
typedef __bf16 bf16x8 __attribute__((ext_vector_type(8)));
typedef float f32x4 __attribute__((ext_vector_type(4)));
typedef float f32x16 __attribute__((ext_vector_type(16)));

__device__ __forceinline__ float elu_f(float v) {
    return v > 0.f ? v : __expf(v) - 1.f;
}

// ---------------------------------------------------------------------------
// K0: prep weights + zero-page.
//   WbT fragment-major: frag f=(i>>4)*2+(o>>5), lane=((i>>3)&1)*32+(o&31), e=i&7
//   WaT fragment-major (same scheme, 16 frags of 512)
//   WcT2 fragment-major Wc for the k_conv epilogue (no LDS stage needed)
//   zp re-zeroed every call (ws is poisoned 0xAA).
// ---------------------------------------------------------------------------
__global__ __launch_bounds__(256) void k_prep(const float* __restrict__ Wb,
                                              const float* __restrict__ Wc,
                                              const float* __restrict__ Wa,
                                              bf16* __restrict__ WbT,
                                              bf16* __restrict__ WcT2,
                                              bf16* __restrict__ WaT,
                                              bf16* __restrict__ zp) {
    int idx = blockIdx.x * 256 + threadIdx.x;
    if (idx < KEEP * HD * HD) {
        int k = idx >> 12;
        int rem = idx & 4095;
        int o = rem >> 6, i = rem & 63;     // o = out-row, i = in-col
        int dst = ((i >> 4) * 2 + (o >> 5)) * 512 +
                  (((i >> 3) & 1) * 32 + (o & 31)) * 8 + (i & 7);
        WbT[(k << 12) + dst] = (bf16)Wb[(k * HD + i) * HD + o];
        return;
    }
    int e = idx - KEEP * HD * HD;
    if (e < CD * HD) {           // WcT2 fragment-major
        int c = e >> 6, h = e & 63;      // c: 0..127, h: 0..63
        int dst = ((c >> 5) * 4 + (h >> 4)) * 512 +
                  ((((h >> 3) & 1) * 32) + (c & 31)) * 8 + (h & 7);
        WcT2[dst] = (bf16)Wc[h * CD + c];
        return;
    }
    e -= CD * HD;
    if (e < HD * CD) {           // WaT, fragment-major
        int o = e >> 7, c = e & 127;
        int dst = ((c >> 4) * 2 + (o >> 5)) * 512 +
                  (((c >> 3) & 1) * 32 + (o & 31)) * 8 + (c & 7);
        WaT[dst] = (bf16)Wa[c * HD + o];
        return;
    }
    e -= HD * CD;
    if (e < 64) zp[e] = (bf16)0.f;
}

// ---------------------------------------------------------------------------
// K1: f[n][h] = elu( elu(x[n]+y[n]) @ Wa ), bf16.  MFMA version.
//   Depth-2 x/y prefetch (triple buffer); coalesced fragment-major WaT issued
//   at iteration top so every vmcnt wait is counted (no drains).
// ---------------------------------------------------------------------------
__global__ __launch_bounds__(256, 4) void k_stage1(const float* __restrict__ x,
                                                   const float* __restrict__ y,
                                                   const bf16* __restrict__ WaT,
                                                   bf16* __restrict__ f) {
    __shared__ bf16 pbuf[4][32 * 64];   // 16 KB, per-wave transpose buffer
    int tid = threadIdx.x;
    int wave = tid >> 6;
    int lane = tid & 63;
    int l31 = lane & 31;
    int half = lane >> 5;
    int pbase_w = blockIdx.x * 128 + wave * 32;
    int p = pbase_w + l31;
    int pc = p < N_PTS ? p : N_PTS - 1;     // clamp loads; stores guarded

    const float* xr = x + (size_t)pc * CD;
    const float* yr = y + (size_t)pc * CD;

    f32x16 acc[2];
#pragma unroll
    for (int mt = 0; mt < 2; mt++)
#pragma unroll
        for (int r = 0; r < 16; r++) acc[mt][r] = 0.f;

    f32x4 xa[3], xb[3], ya[3], yb[3];
#pragma unroll
    for (int pre = 0; pre < 2; pre++) {
        int c0 = half * 8 + pre * 16;
        xa[pre] = *(const f32x4*)(xr + c0);
        xb[pre] = *(const f32x4*)(xr + c0 + 4);
        ya[pre] = *(const f32x4*)(yr + c0);
        yb[pre] = *(const f32x4*)(yr + c0 + 4);
    }
#pragma unroll
    for (int ks = 0; ks < 8; ks++) {
        int cur = ks % 3, nxt = (ks + 2) % 3;
        bf16x8 a0 = *(const bf16x8*)(WaT + (ks * 2 + 0) * 512 + lane * 8);
        bf16x8 a1 = *(const bf16x8*)(WaT + (ks * 2 + 1) * 512 + lane * 8);
        __builtin_amdgcn_sched_barrier(0);
        if (ks < 6) {
            int c0 = half * 8 + (ks + 2) * 16;
            xa[nxt] = *(const f32x4*)(xr + c0);
            xb[nxt] = *(const f32x4*)(xr + c0 + 4);
            ya[nxt] = *(const f32x4*)(yr + c0);
            yb[nxt] = *(const f32x4*)(yr + c0 + 4);
        }
        bf16x8 bv;
#pragma unroll
        for (int jj = 0; jj < 4; jj++) {
            bv[jj]     = (bf16)elu_f(xa[cur][jj] + ya[cur][jj]);
            bv[4 + jj] = (bf16)elu_f(xb[cur][jj] + yb[cur][jj]);
        }
        acc[0] = __builtin_amdgcn_mfma_f32_32x32x16_bf16(a0, bv, acc[0], 0, 0, 0);
        acc[1] = __builtin_amdgcn_mfma_f32_32x32x16_bf16(a1, bv, acc[1], 0, 0, 0);
        __builtin_amdgcn_sched_barrier(0);
    }

    // elu + scatter into pbuf [point][h] (XOR-swizzled 16B chunks), then
    // coalesced 16B stores.  Per-wave buffer: no barrier needed.
    bf16* pb = pbuf[wave];
#pragma unroll
    for (int mt = 0; mt < 2; mt++) {
#pragma unroll
        for (int q = 0; q < 4; q++) {
            bf16x4 v;
#pragma unroll
            for (int jj = 0; jj < 4; jj++)
                v[jj] = (bf16)elu_f(acc[mt][q * 4 + jj]);
            int chunk = mt * 4 + q;   // h = chunk*8 + 4*half + j
            *(bf16x4*)&pb[l31 * 64 + ((chunk ^ (l31 & 7)) * 8) + 4 * half] = v;
        }
    }
#pragma unroll
    for (int qq = 0; qq < 4; qq++) {
        int t = lane + 64 * qq;          // 0..255 chunk ids
        int row = t >> 3, ch = t & 7;
        int pos = ch ^ (row & 7);
        bf16x8 v = *(const bf16x8*)&pb[row * 64 + pos * 8];
        int pp = pbase_w + row;
        if (pp < N_PTS)
            *(bf16x8*)(f + (size_t)pp * HD + ch * 8) = v;
    }
}

// ---------------------------------------------------------------------------
// K2: conv + fused epilogue.  32 pts/wave, 4 waves/wg, NO barriers.
//   Group-of-8 gather: 8 lanes cooperatively load one full 128B f-row in ONE
//   instruction -> 4 insts / 32 line-touches per substep (vs 128 in the
//   round-1 per-lane gather: the TA redundancy the counters pointed at).
//   Gathered rows bounce through a per-wave 4KB LDS buffer (XOR-swizzled) to
//   reach MFMA B-frag layout.  Single buffer: frag reads of tile k precede
//   writes of tile k+1 in program order; per-wave DS pipe is in-order.
//   Pipeline (ALL waits counted, no drains):
//     A(k) double-buffered      : loaded 1 substep ahead  (~400+ cyc slack)
//     gathers (rows k+2)        : 2 substeps ahead
//     idx (4 rotating slots)    : 4 substeps ahead        (covers ~900cyc HBM)
//   Substep: [A(k+1) 8ld][gather(k+2) 4ld + idx(k+6) 4ld][MFMA(k) 8x]
//            [ds_write rows k+1]
// ---------------------------------------------------------------------------
struct GR { bf16x8 v[4]; };
struct AF { bf16x8 v[8]; };

__global__ __launch_bounds__(256, 4) void k_conv(const bf16* __restrict__ f,
                                                 const int* __restrict__ nidx,
                                                 const bf16* __restrict__ WbT,
                                                 const bf16* __restrict__ WcT2,
                                                 const bf16* __restrict__ zp,
                                                 const float* __restrict__ x,
                                                 float* __restrict__ out) {
    __shared__ bf16 bounce[4][32 * 64];   // 16 KB: per-wave gather-transpose buf

    int tid = threadIdx.x;
    int wave = tid >> 6;
    int lane = tid & 63;
    int l31 = lane & 31;
    int half = lane >> 5;
    int g8 = lane >> 3;        // group id 0..7 (row within gather inst)
    int l7 = lane & 7;         // lane-in-group (16B chunk of the row)
    int pbase = blockIdx.x * 128 + wave * 32;

    bf16* pb = bounce[wave];

    f32x16 acc[2];
#pragma unroll
    for (int mt = 0; mt < 2; mt++)
#pragma unroll
        for (int r = 0; r < 16; r++) acc[mt][r] = 0.f;

    // idx for gather-inst i of offset k: point = pbase + i*8 + g8
    auto ldidx4 = [&](int k, int i) -> int {
        int pp = pbase + i * 8 + g8;
        return (k < KEEP && pp < N_PTS) ? nidx[(size_t)k * N_PTS + pp] : -1;
    };
    auto gaddr = [&](int iv) -> const bf16* {
        return iv >= 0 ? f + (size_t)iv * HD + l7 * 8 : zp + l7 * 8;
    };
    auto gather4 = [&](GR& g, const int (&iv)[4]) {
#pragma unroll
        for (int i = 0; i < 4; i++)
            g.v[i] = *(const bf16x8*)gaddr(iv[i]);
    };
    // scatter gathered rows (lane-group layout) into bounce, XOR-swizzled:
    // chunk c of row pp lands at position (c ^ (pp&7)); here c=l7, pp&7=g8.
    auto dswrite = [&](const GR& g) {
#pragma unroll
        for (int i = 0; i < 4; i++) {
            int pp = i * 8 + g8;                       // row 0..31
            *(bf16x8*)&pb[pp * 64 + ((l7 ^ g8) * 8)] = g.v[i];
        }
    };
    auto loadA = [&](int k, AF& A) {
        const bf16* wk = WbT + ((size_t)k << 12);
#pragma unroll
        for (int fi = 0; fi < 8; fi++)     // 8 fully-coalesced 1KB wave reads
            A.v[fi] = *(const bf16x8*)(wk + fi * 512 + lane * 8);
    };
    auto mfma8 = [&](const AF& a) {
#pragma unroll
        for (int ks = 0; ks < 4; ks++) {
            int ci = ks * 2 + half;
            bf16x8 fb = *(const bf16x8*)&pb[l31 * 64 + ((ci ^ (l31 & 7)) * 8)];
            acc[0] = __builtin_amdgcn_mfma_f32_32x32x16_bf16(a.v[ks * 2 + 0], fb, acc[0], 0, 0, 0);
            acc[1] = __builtin_amdgcn_mfma_f32_32x32x16_bf16(a.v[ks * 2 + 1], fb, acc[1], 0, 0, 0);
        }
    };
    // substep k: issue A(k+1), gather rows k+2, refill slot with idx(k+6),
    // compute k from bounce with A(k), write rows k+1 to bounce.
    auto substep = [&](int k, AF& Aload, const AF& Ause, GR& gfill,
                       const GR& gwrite, int (&slot)[4]) {
        loadA(k + 1, Aload);
        __builtin_amdgcn_sched_barrier(0);
        gather4(gfill, slot);
#pragma unroll
        for (int i = 0; i < 4; i++) slot[i] = ldidx4(k + 6, i);
        __builtin_amdgcn_sched_barrier(0);
        mfma8(Ause);
        __builtin_amdgcn_sched_barrier(0);
        dswrite(gwrite);
        __builtin_amdgcn_sched_barrier(0);
    };

    // ---- prologue ----
    int s0[4], s1[4], s2[4], s3[4];   // rotating idx slots, depth-4
#pragma unroll
    for (int i = 0; i < 4; i++) s0[i] = ldidx4(2, i);
#pragma unroll
    for (int i = 0; i < 4; i++) s1[i] = ldidx4(3, i);
#pragma unroll
    for (int i = 0; i < 4; i++) s2[i] = ldidx4(4, i);
#pragma unroll
    for (int i = 0; i < 4; i++) s3[i] = ldidx4(5, i);
    AF A0, A1;
    GR ge, go;
    {
        int i0[4], i1[4];
#pragma unroll
        for (int i = 0; i < 4; i++) i0[i] = ldidx4(0, i);
#pragma unroll
        for (int i = 0; i < 4; i++) i1[i] = ldidx4(1, i);
        GR g0;
        gather4(g0, i0);        // rows k=0
        gather4(go, i1);        // rows k=1 (written at substep 0)
        dswrite(g0);            // bounce holds k=0
        loadA(0, A0);
    }

    // ---- main loop: k = 0..59 ----
    for (int j = 0; j < 15; j++) {
        int k = 4 * j;
        substep(k,     A1, A0, ge, go, s0);
        substep(k + 1, A0, A1, go, ge, s1);
        substep(k + 2, A1, A0, ge, go, s2);
        substep(k + 3, A0, A1, go, ge, s3);
    }
    substep(60, A1, A0, ge, go, s0);
    substep(61, A0, A1, go, ge, s1);
    // ---- tail: k = 62 (A0 holds A(62), bounce holds rows 62) ----
    mfma8(A0);

    // ---- epilogue: out[p][c] = x[p][c] + elu(acc)^T @ Wc ----
    // P-transpose through bounce (per-wave, in-order DS, no barrier), Wc
    // frags direct from global (L2-hot, coalesced 1KB reads).
#pragma unroll
    for (int mt = 0; mt < 2; mt++) {
#pragma unroll
        for (int q = 0; q < 4; q++) {
            bf16x4 v;
#pragma unroll
            for (int jj = 0; jj < 4; jj++)
                v[jj] = (bf16)elu_f(acc[mt][q * 4 + jj]);
            int chunk = mt * 4 + q;   // h = chunk*8 + 4*half + j
            *(bf16x4*)&pb[l31 * 64 + ((chunk ^ (l31 & 7)) * 8) + 4 * half] = v;
        }
    }
    bf16x8 pa[4];
#pragma unroll
    for (int ks = 0; ks < 4; ks++) {
        int ci = 2 * ks + half;
        pa[ks] = *(const bf16x8*)&pb[l31 * 64 + ((ci ^ (l31 & 7)) * 8)];
    }
#pragma unroll
    for (int ct = 0; ct < 4; ct++) {
        f32x16 o;
#pragma unroll
        for (int r = 0; r < 16; r++) o[r] = 0.f;
        int cc = ct * 32 + l31;
#pragma unroll
        for (int ks = 0; ks < 4; ks++) {
            bf16x8 bw = *(const bf16x8*)(WcT2 + ((ct * 4 + ks) << 9) + lane * 8);
            o = __builtin_amdgcn_mfma_f32_32x32x16_bf16(pa[ks], bw, o, 0, 0, 0);
        }
        int prow_base = pbase + 4 * half;
#pragma unroll
        for (int r = 0; r < 16; r++) {
            int prow = prow_base + (r & 3) + 8 * (r >> 2);
            if (prow < N_PTS) {
                size_t off = (size_t)prow * CD + cc;
                out[off] = x[off] + o[r];
            }
        }
    }
}

// ---------------------------------------------------------------------------
extern "C" void kernel_launch(void* const* d_in, const int* in_sizes, int n_in,
                              void* d_out, int out_size, void* d_ws, size_t ws_size,
                              hipStream_t stream) {
    const float* x  = (const float*)d_in[0];
    const float* y  = (const float*)d_in[1];
    const float* Wa = (const float*)d_in[2];
    const float* Wb = (const float*)d_in[3];
    const float* Wc = (const float*)d_in[4];
    const int* nidx = (const int*)d_in[5];
    float* out = (float*)d_out;

    char* ws = (char*)d_ws;
    bf16* f    = (bf16*)ws;                           // 200192*64*2 = 25,624,576 B
    bf16* WbT  = (bf16*)(ws + 25624576);              // 63*4096*2   =    516,096 B
    bf16* WcT2 = (bf16*)(ws + 25624576 + 516096);     // 8192*2      =     16,384 B
    bf16* WaT  = (bf16*)(ws + 25624576 + 516096 + 16384);   // 8192*2 = 16,384 B
    bf16* zp   = (bf16*)(ws + 25624576 + 516096 + 16384 + 16384);  // 128 B zeros

    k_prep<<<1073, 256, 0, stream>>>(Wb, Wc, Wa, WbT, WcT2, WaT, zp);
    k_stage1<<<1563, 256, 0, stream>>>(x, y, WaT, f);
    k_conv<<<1563, 256, 0, stream>>>(f, nidx, WbT, WcT2, zp, x, out);
}

// Round 4
// 539.501 us; speedup vs baseline: 2.8706x; 2.8706x over previous
//
#include <hip/hip_runtime.h>
#include <cmath>

#define N_PTS 200000
#define HD 64
#define CD 128
#define KEEP 63

typedef __bf16 bf16;
typedef __bf16 bf16x4 __attribute__((ext_vector_type(4)));
typedef __bf16 bf16x8 __attribute__((ext_vector_type(8)));
typedef float f32x4 __attribute__((ext_vector_type(4)));
typedef float f32x16 __attribute__((ext_vector_type(16)));

__device__ __forceinline__ float elu_f(float v) {
    return v > 0.f ? v : __expf(v) - 1.f;
}

// ---------------------------------------------------------------------------
// K0: prep weights + zero-page.
//   WbT fragment-major: frag f=(i>>4)*2+(o>>5), lane=((i>>3)&1)*32+(o&31), e=i&7
//   WaT fragment-major (same scheme, 16 frags of 512)
//   WcT2 fragment-major Wc for the k_conv epilogue
//   zp re-zeroed every call (ws is poisoned 0xAA).
// ---------------------------------------------------------------------------
__global__ __launch_bounds__(256) void k_prep(const float* __restrict__ Wb,
                                              const float* __restrict__ Wc,
                                              const float* __restrict__ Wa,
                                              bf16* __restrict__ WbT,
                                              bf16* __restrict__ WcT2,
                                              bf16* __restrict__ WaT,
                                              bf16* __restrict__ zp) {
    int idx = blockIdx.x * 256 + threadIdx.x;
    if (idx < KEEP * HD * HD) {
        int k = idx >> 12;
        int rem = idx & 4095;
        int o = rem >> 6, i = rem & 63;     // o = out-row, i = in-col
        int dst = ((i >> 4) * 2 + (o >> 5)) * 512 +
                  (((i >> 3) & 1) * 32 + (o & 31)) * 8 + (i & 7);
        WbT[(k << 12) + dst] = (bf16)Wb[(k * HD + i) * HD + o];
        return;
    }
    int e = idx - KEEP * HD * HD;
    if (e < CD * HD) {           // WcT2 fragment-major
        int c = e >> 6, h = e & 63;      // c: 0..127, h: 0..63
        int dst = ((c >> 5) * 4 + (h >> 4)) * 512 +
                  ((((h >> 3) & 1) * 32) + (c & 31)) * 8 + (h & 7);
        WcT2[dst] = (bf16)Wc[h * CD + c];
        return;
    }
    e -= CD * HD;
    if (e < HD * CD) {           // WaT, fragment-major
        int o = e >> 7, c = e & 127;
        int dst = ((c >> 4) * 2 + (o >> 5)) * 512 +
                  (((c >> 3) & 1) * 32 + (o & 31)) * 8 + (c & 7);
        WaT[dst] = (bf16)Wa[c * HD + o];
        return;
    }
    e -= HD * CD;
    if (e < 64) zp[e] = (bf16)0.f;
}

// ---------------------------------------------------------------------------
// K1: f[n][h] = elu( elu(x[n]+y[n]) @ Wa ), bf16.  (round-1-proven version:
//   depth-1 x/y prefetch = double buffer, ~96 regs, safely under the 128 cap
//   of launch_bounds(256,4).)
// ---------------------------------------------------------------------------
__global__ __launch_bounds__(256, 4) void k_stage1(const float* __restrict__ x,
                                                   const float* __restrict__ y,
                                                   const bf16* __restrict__ WaT,
                                                   bf16* __restrict__ f) {
    __shared__ bf16 pbuf[4][32 * 64];   // 16 KB, per-wave transpose buffer
    int tid = threadIdx.x;
    int wave = tid >> 6;
    int lane = tid & 63;
    int l31 = lane & 31;
    int half = lane >> 5;
    int pbase_w = blockIdx.x * 128 + wave * 32;
    int p = pbase_w + l31;
    int pc = p < N_PTS ? p : N_PTS - 1;     // clamp loads; stores guarded

    const float* xr = x + (size_t)pc * CD;
    const float* yr = y + (size_t)pc * CD;

    f32x16 acc[2];
#pragma unroll
    for (int mt = 0; mt < 2; mt++)
#pragma unroll
        for (int r = 0; r < 16; r++) acc[mt][r] = 0.f;

    f32x4 xa[2], xb[2], ya[2], yb[2];
    {
        int c0 = half * 8;
        xa[0] = *(const f32x4*)(xr + c0);
        xb[0] = *(const f32x4*)(xr + c0 + 4);
        ya[0] = *(const f32x4*)(yr + c0);
        yb[0] = *(const f32x4*)(yr + c0 + 4);
    }
#pragma unroll
    for (int ks = 0; ks < 8; ks++) {
        int cur = ks & 1, nxt = cur ^ 1;
        bf16x8 a0 = *(const bf16x8*)(WaT + (ks * 2 + 0) * 512 + lane * 8);
        bf16x8 a1 = *(const bf16x8*)(WaT + (ks * 2 + 1) * 512 + lane * 8);
        __builtin_amdgcn_sched_barrier(0);
        if (ks < 7) {
            int c0 = half * 8 + (ks + 1) * 16;
            xa[nxt] = *(const f32x4*)(xr + c0);
            xb[nxt] = *(const f32x4*)(xr + c0 + 4);
            ya[nxt] = *(const f32x4*)(yr + c0);
            yb[nxt] = *(const f32x4*)(yr + c0 + 4);
        }
        bf16x8 bv;
#pragma unroll
        for (int jj = 0; jj < 4; jj++) {
            bv[jj]     = (bf16)elu_f(xa[cur][jj] + ya[cur][jj]);
            bv[4 + jj] = (bf16)elu_f(xb[cur][jj] + yb[cur][jj]);
        }
        acc[0] = __builtin_amdgcn_mfma_f32_32x32x16_bf16(a0, bv, acc[0], 0, 0, 0);
        acc[1] = __builtin_amdgcn_mfma_f32_32x32x16_bf16(a1, bv, acc[1], 0, 0, 0);
        __builtin_amdgcn_sched_barrier(0);
    }

    // elu + scatter into pbuf [point][h] (XOR-swizzled 16B chunks), then
    // coalesced 16B stores.  Per-wave buffer: no barrier needed.
    bf16* pb = pbuf[wave];
#pragma unroll
    for (int mt = 0; mt < 2; mt++) {
#pragma unroll
        for (int q = 0; q < 4; q++) {
            bf16x4 v;
#pragma unroll
            for (int jj = 0; jj < 4; jj++)
                v[jj] = (bf16)elu_f(acc[mt][q * 4 + jj]);
            int chunk = mt * 4 + q;   // h = chunk*8 + 4*half + j
            *(bf16x4*)&pb[l31 * 64 + ((chunk ^ (l31 & 7)) * 8) + 4 * half] = v;
        }
    }
#pragma unroll
    for (int qq = 0; qq < 4; qq++) {
        int t = lane + 64 * qq;          // 0..255 chunk ids
        int row = t >> 3, ch = t & 7;
        int pos = ch ^ (row & 7);
        bf16x8 v = *(const bf16x8*)&pb[row * 64 + pos * 8];
        int pp = pbase_w + row;
        if (pp < N_PTS)
            *(bf16x8*)(f + (size_t)pp * HD + ch * 8) = v;
    }
}

// ---------------------------------------------------------------------------
// K2: conv + fused epilogue.  32 pts/wave, 4 waves/wg, NO barriers.
//   Group-of-8 gather: 8 lanes cooperatively load one full 128B f-row in ONE
//   instruction -> 4 insts / 32 line-touches per substep (vs 128 per-lane).
//   Gathered rows bounce through a per-wave 4KB LDS buffer (XOR-swizzled) to
//   reach MFMA B-frag layout; per-wave DS pipe is in-order, no sync needed.
//
//   ROUND-4 FIX: launch_bounds(256,2) — the round-3 (256,4)=128-reg cap
//   forced a massive scratch spill (WRITE_SIZE 2.45GB, VGPR=64+spill).
//   A-dbuf dropped (-32 regs): A waits are still counted (vmcnt(8), gathers
//   +idx issued after it), remainder covered by TLP.  Demand ~150-165 regs
//   -> 3 waves/SIMD tier, zero scratch.
//   Pipeline: gathers 2 substeps ahead; idx 4 rotating slots (covers ~900cyc
//   HBM); A issued at substep top, consumed same substep.
// ---------------------------------------------------------------------------
struct GR { bf16x8 v[4]; };
struct AF { bf16x8 v[8]; };

__global__ __launch_bounds__(256, 2) void k_conv(const bf16* __restrict__ f,
                                                 const int* __restrict__ nidx,
                                                 const bf16* __restrict__ WbT,
                                                 const bf16* __restrict__ WcT2,
                                                 const bf16* __restrict__ zp,
                                                 const float* __restrict__ x,
                                                 float* __restrict__ out) {
    __shared__ bf16 bounce[4][32 * 64];   // 16 KB: per-wave gather-transpose buf

    int tid = threadIdx.x;
    int wave = tid >> 6;
    int lane = tid & 63;
    int l31 = lane & 31;
    int half = lane >> 5;
    int g8 = lane >> 3;        // group id 0..7 (row within gather inst)
    int l7 = lane & 7;         // lane-in-group (16B chunk of the row)
    int pbase = blockIdx.x * 128 + wave * 32;

    bf16* pb = bounce[wave];

    f32x16 acc[2];
#pragma unroll
    for (int mt = 0; mt < 2; mt++)
#pragma unroll
        for (int r = 0; r < 16; r++) acc[mt][r] = 0.f;

    // idx for gather-inst i of offset k: point = pbase + i*8 + g8
    auto ldidx4 = [&](int k, int i) -> int {
        int pp = pbase + i * 8 + g8;
        return (k < KEEP && pp < N_PTS) ? nidx[(size_t)k * N_PTS + pp] : -1;
    };
    auto gaddr = [&](int iv) -> const bf16* {
        return iv >= 0 ? f + (size_t)iv * HD + l7 * 8 : zp + l7 * 8;
    };
    auto gather4 = [&](GR& g, const int (&iv)[4]) {
#pragma unroll
        for (int i = 0; i < 4; i++)
            g.v[i] = *(const bf16x8*)gaddr(iv[i]);
    };
    // scatter gathered rows (lane-group layout) into bounce, XOR-swizzled:
    // chunk c of row pp lands at position (c ^ (pp&7)); here c=l7, pp&7=g8.
    auto dswrite = [&](const GR& g) {
#pragma unroll
        for (int i = 0; i < 4; i++) {
            int pp = i * 8 + g8;                       // row 0..31
            *(bf16x8*)&pb[pp * 64 + ((l7 ^ g8) * 8)] = g.v[i];
        }
    };
    auto loadA = [&](int k, AF& A) {
        const bf16* wk = WbT + ((size_t)k << 12);
#pragma unroll
        for (int fi = 0; fi < 8; fi++)     // 8 fully-coalesced 1KB wave reads
            A.v[fi] = *(const bf16x8*)(wk + fi * 512 + lane * 8);
    };
    auto mfma8 = [&](const AF& a) {
#pragma unroll
        for (int ks = 0; ks < 4; ks++) {
            int ci = ks * 2 + half;
            bf16x8 fb = *(const bf16x8*)&pb[l31 * 64 + ((ci ^ (l31 & 7)) * 8)];
            acc[0] = __builtin_amdgcn_mfma_f32_32x32x16_bf16(a.v[ks * 2 + 0], fb, acc[0], 0, 0, 0);
            acc[1] = __builtin_amdgcn_mfma_f32_32x32x16_bf16(a.v[ks * 2 + 1], fb, acc[1], 0, 0, 0);
        }
    };
    // substep k: issue A(k), gather rows k+2, refill slot with idx(k+6),
    // compute k from bounce with A(k), write rows k+1 to bounce.
    auto substep = [&](int k, GR& gfill, const GR& gwrite, int (&slot)[4]) {
        AF a;
        loadA(k, a);
        __builtin_amdgcn_sched_barrier(0);
        gather4(gfill, slot);
#pragma unroll
        for (int i = 0; i < 4; i++) slot[i] = ldidx4(k + 6, i);
        __builtin_amdgcn_sched_barrier(0);
        mfma8(a);
        __builtin_amdgcn_sched_barrier(0);
        dswrite(gwrite);
        __builtin_amdgcn_sched_barrier(0);
    };

    // ---- prologue ----
    int s0[4], s1[4], s2[4], s3[4];   // rotating idx slots, depth-4
#pragma unroll
    for (int i = 0; i < 4; i++) s0[i] = ldidx4(2, i);
#pragma unroll
    for (int i = 0; i < 4; i++) s1[i] = ldidx4(3, i);
#pragma unroll
    for (int i = 0; i < 4; i++) s2[i] = ldidx4(4, i);
#pragma unroll
    for (int i = 0; i < 4; i++) s3[i] = ldidx4(5, i);
    GR ge, go;
    {
        int i0[4], i1[4];
#pragma unroll
        for (int i = 0; i < 4; i++) i0[i] = ldidx4(0, i);
#pragma unroll
        for (int i = 0; i < 4; i++) i1[i] = ldidx4(1, i);
        GR g0;
        gather4(g0, i0);        // rows k=0
        gather4(go, i1);        // rows k=1 (written at substep 0)
        dswrite(g0);            // bounce holds k=0
    }

    // ---- main loop: k = 0..61 ----
    // even substep: fill ge (rows k+2), write go (rows k+1); odd: swap.
    for (int j = 0; j < 15; j++) {
        int k = 4 * j;
        substep(k,     ge, go, s0);
        substep(k + 1, go, ge, s1);
        substep(k + 2, ge, go, s2);
        substep(k + 3, go, ge, s3);
    }
    substep(60, ge, go, s0);
    substep(61, go, ge, s1);
    // ---- tail: k = 62 (bounce holds rows 62) ----
    {
        AF a;
        loadA(62, a);
        mfma8(a);
    }

    // ---- epilogue: out[p][c] = x[p][c] + elu(acc)^T @ Wc ----
    // P-transpose through bounce (per-wave, in-order DS, no barrier), Wc
    // frags direct from global (L2-hot, coalesced 1KB reads).
#pragma unroll
    for (int mt = 0; mt < 2; mt++) {
#pragma unroll
        for (int q = 0; q < 4; q++) {
            bf16x4 v;
#pragma unroll
            for (int jj = 0; jj < 4; jj++)
                v[jj] = (bf16)elu_f(acc[mt][q * 4 + jj]);
            int chunk = mt * 4 + q;   // h = chunk*8 + 4*half + j
            *(bf16x4*)&pb[l31 * 64 + ((chunk ^ (l31 & 7)) * 8) + 4 * half] = v;
        }
    }
    bf16x8 pa[4];
#pragma unroll
    for (int ks = 0; ks < 4; ks++) {
        int ci = 2 * ks + half;
        pa[ks] = *(const bf16x8*)&pb[l31 * 64 + ((ci ^ (l31 & 7)) * 8)];
    }
#pragma unroll
    for (int ct = 0; ct < 4; ct++) {
        f32x16 o;
#pragma unroll
        for (int r = 0; r < 16; r++) o[r] = 0.f;
        int cc = ct * 32 + l31;
#pragma unroll
        for (int ks = 0; ks < 4; ks++) {
            bf16x8 bw = *(const bf16x8*)(WcT2 + ((ct * 4 + ks) << 9) + lane * 8);
            o = __builtin_amdgcn_mfma_f32_32x32x16_bf16(pa[ks], bw, o, 0, 0, 0);
        }
        int prow_base = pbase + 4 * half;
#pragma unroll
        for (int r = 0; r < 16; r++) {
            int prow = prow_base + (r & 3) + 8 * (r >> 2);
            if (prow < N_PTS) {
                size_t off = (size_t)prow * CD + cc;
                out[off] = x[off] + o[r];
            }
        }
    }
}

// ---------------------------------------------------------------------------
extern "C" void kernel_launch(void* const* d_in, const int* in_sizes, int n_in,
                              void* d_out, int out_size, void* d_ws, size_t ws_size,
                              hipStream_t stream) {
    const float* x  = (const float*)d_in[0];
    const float* y  = (const float*)d_in[1];
    const float* Wa = (const float*)d_in[2];
    const float* Wb = (const float*)d_in[3];
    const float* Wc = (const float*)d_in[4];
    const int* nidx = (const int*)d_in[5];
    float* out = (float*)d_out;

    char* ws = (char*)d_ws;
    bf16* f    = (bf16*)ws;                           // 200192*64*2 = 25,624,576 B
    bf16* WbT  = (bf16*)(ws + 25624576);              // 63*4096*2   =    516,096 B
    bf16* WcT2 = (bf16*)(ws + 25624576 + 516096);     // 8192*2      =     16,384 B
    bf16* WaT  = (bf16*)(ws + 25624576 + 516096 + 16384);   // 8192*2 = 16,384 B
    bf16* zp   = (bf16*)(ws + 25624576 + 516096 + 16384 + 16384);  // 128 B zeros

    k_prep<<<1073, 256, 0, stream>>>(Wb, Wc, Wa, WbT, WcT2, WaT, zp);
    k_stage1<<<1563, 256, 0, stream>>>(x, y, WaT, f);
    k_conv<<<1563, 256, 0, stream>>>(f, nidx, WbT, WcT2, zp, x, out);
}

// Round 5
// 501.707 us; speedup vs baseline: 3.0868x; 1.0753x over previous
//
#include <hip/hip_runtime.h>
#include <cmath>

#define N_PTS 200000
#define HD 64
#define CD 128
#define KEEP 63

typedef __bf16 bf16;
typedef __bf16 bf16x4 __attribute__((ext_vector_type(4)));
typedef __bf16 bf16x8 __attribute__((ext_vector_type(8)));
typedef float f32x4 __attribute__((ext_vector_type(4)));
typedef float f32x16 __attribute__((ext_vector_type(16)));

__device__ __forceinline__ float elu_f(float v) {
    return v > 0.f ? v : __expf(v) - 1.f;
}

// ---------------------------------------------------------------------------
// K0: prep weights + zero-page.
//   WbT fragment-major: frag f=(i>>4)*2+(o>>5), lane=((i>>3)&1)*32+(o&31), e=i&7
//   WaT fragment-major (same scheme, 16 frags of 512)
//   WcT2 fragment-major Wc for the k_conv epilogue
//   zp re-zeroed every call (ws is poisoned 0xAA).
// ---------------------------------------------------------------------------
__global__ __launch_bounds__(256) void k_prep(const float* __restrict__ Wb,
                                              const float* __restrict__ Wc,
                                              const float* __restrict__ Wa,
                                              bf16* __restrict__ WbT,
                                              bf16* __restrict__ WcT2,
                                              bf16* __restrict__ WaT,
                                              bf16* __restrict__ zp) {
    int idx = blockIdx.x * 256 + threadIdx.x;
    if (idx < KEEP * HD * HD) {
        int k = idx >> 12;
        int rem = idx & 4095;
        int o = rem >> 6, i = rem & 63;     // o = out-row, i = in-col
        int dst = ((i >> 4) * 2 + (o >> 5)) * 512 +
                  (((i >> 3) & 1) * 32 + (o & 31)) * 8 + (i & 7);
        WbT[(k << 12) + dst] = (bf16)Wb[(k * HD + i) * HD + o];
        return;
    }
    int e = idx - KEEP * HD * HD;
    if (e < CD * HD) {           // WcT2 fragment-major
        int c = e >> 6, h = e & 63;      // c: 0..127, h: 0..63
        int dst = ((c >> 5) * 4 + (h >> 4)) * 512 +
                  ((((h >> 3) & 1) * 32) + (c & 31)) * 8 + (h & 7);
        WcT2[dst] = (bf16)Wc[h * CD + c];
        return;
    }
    e -= CD * HD;
    if (e < HD * CD) {           // WaT, fragment-major
        int o = e >> 7, c = e & 127;
        int dst = ((c >> 4) * 2 + (o >> 5)) * 512 +
                  (((c >> 3) & 1) * 32 + (o & 31)) * 8 + (c & 7);
        WaT[dst] = (bf16)Wa[c * HD + o];
        return;
    }
    e -= HD * CD;
    if (e < 64) zp[e] = (bf16)0.f;
}

// ---------------------------------------------------------------------------
// K1: f[n][h] = elu( elu(x[n]+y[n]) @ Wa ), bf16.  (round-1-proven version,
//   unchanged this round: one mechanism per round.)
// ---------------------------------------------------------------------------
__global__ __launch_bounds__(256, 4) void k_stage1(const float* __restrict__ x,
                                                   const float* __restrict__ y,
                                                   const bf16* __restrict__ WaT,
                                                   bf16* __restrict__ f) {
    __shared__ bf16 pbuf[4][32 * 64];   // 16 KB, per-wave transpose buffer
    int tid = threadIdx.x;
    int wave = tid >> 6;
    int lane = tid & 63;
    int l31 = lane & 31;
    int half = lane >> 5;
    int pbase_w = blockIdx.x * 128 + wave * 32;
    int p = pbase_w + l31;
    int pc = p < N_PTS ? p : N_PTS - 1;     // clamp loads; stores guarded

    const float* xr = x + (size_t)pc * CD;
    const float* yr = y + (size_t)pc * CD;

    f32x16 acc[2];
#pragma unroll
    for (int mt = 0; mt < 2; mt++)
#pragma unroll
        for (int r = 0; r < 16; r++) acc[mt][r] = 0.f;

    f32x4 xa[2], xb[2], ya[2], yb[2];
    {
        int c0 = half * 8;
        xa[0] = *(const f32x4*)(xr + c0);
        xb[0] = *(const f32x4*)(xr + c0 + 4);
        ya[0] = *(const f32x4*)(yr + c0);
        yb[0] = *(const f32x4*)(yr + c0 + 4);
    }
#pragma unroll
    for (int ks = 0; ks < 8; ks++) {
        int cur = ks & 1, nxt = cur ^ 1;
        bf16x8 a0 = *(const bf16x8*)(WaT + (ks * 2 + 0) * 512 + lane * 8);
        bf16x8 a1 = *(const bf16x8*)(WaT + (ks * 2 + 1) * 512 + lane * 8);
        __builtin_amdgcn_sched_barrier(0);
        if (ks < 7) {
            int c0 = half * 8 + (ks + 1) * 16;
            xa[nxt] = *(const f32x4*)(xr + c0);
            xb[nxt] = *(const f32x4*)(xr + c0 + 4);
            ya[nxt] = *(const f32x4*)(yr + c0);
            yb[nxt] = *(const f32x4*)(yr + c0 + 4);
        }
        bf16x8 bv;
#pragma unroll
        for (int jj = 0; jj < 4; jj++) {
            bv[jj]     = (bf16)elu_f(xa[cur][jj] + ya[cur][jj]);
            bv[4 + jj] = (bf16)elu_f(xb[cur][jj] + yb[cur][jj]);
        }
        acc[0] = __builtin_amdgcn_mfma_f32_32x32x16_bf16(a0, bv, acc[0], 0, 0, 0);
        acc[1] = __builtin_amdgcn_mfma_f32_32x32x16_bf16(a1, bv, acc[1], 0, 0, 0);
        __builtin_amdgcn_sched_barrier(0);
    }

    // elu + scatter into pbuf [point][h] (XOR-swizzled 16B chunks), then
    // coalesced 16B stores.  Per-wave buffer: no barrier needed.
    bf16* pb = pbuf[wave];
#pragma unroll
    for (int mt = 0; mt < 2; mt++) {
#pragma unroll
        for (int q = 0; q < 4; q++) {
            bf16x4 v;
#pragma unroll
            for (int jj = 0; jj < 4; jj++)
                v[jj] = (bf16)elu_f(acc[mt][q * 4 + jj]);
            int chunk = mt * 4 + q;   // h = chunk*8 + 4*half + j
            *(bf16x4*)&pb[l31 * 64 + ((chunk ^ (l31 & 7)) * 8) + 4 * half] = v;
        }
    }
#pragma unroll
    for (int qq = 0; qq < 4; qq++) {
        int t = lane + 64 * qq;          // 0..255 chunk ids
        int row = t >> 3, ch = t & 7;
        int pos = ch ^ (row & 7);
        bf16x8 v = *(const bf16x8*)&pb[row * 64 + pos * 8];
        int pp = pbase_w + row;
        if (pp < N_PTS)
            *(bf16x8*)(f + (size_t)pp * HD + ch * 8) = v;
    }
}

// ---------------------------------------------------------------------------
// K2: conv + fused epilogue.  32 pts/wave, 4 waves/wg.
//   ROUND-5: A(k) staged in LDS, double-buffered, SHARED by the 4 waves
//   (they consume identical A(k) each substep):
//     - removes the per-substep exposed A-latency (round-4's wall: loadA
//       consumed same substep, ~L2 RTT x 63 with only 2 waves/SIMD to hide)
//     - cuts A global traffic 4x (8KB/substep/block instead of per-wave)
//     - LOWERS register demand (no 32-reg A-frag block live across MFMAs)
//   Sync: raw s_barrier per substep (NOT __syncthreads: that emits vmcnt(0)
//   and would drain the gather/idx prefetch queue).  Reg-staged T14 split:
//   stage-loads issued FIRST in the substep, ds_write LAST -> compiler emits
//   counted vmcnt(8) for the stage, vmcnt(14) for the bounce dswrite; gathers
//   keep 2 substeps slack, idx 4.  lgkmcnt(0) before each barrier gives
//   cross-wave LDS visibility.
//   Race audit: substep k reads lds_a[k&1], stage-writes (k+1)&1; a wave
//   reaches substep k+1 (writing k&1) only after the end-of-k barrier, by
//   which point ALL waves finished their k&1 reads.  All barriers uniform.
// ---------------------------------------------------------------------------
struct GR { bf16x8 v[4]; };

__global__ __launch_bounds__(256, 2) void k_conv(const bf16* __restrict__ f,
                                                 const int* __restrict__ nidx,
                                                 const bf16* __restrict__ WbT,
                                                 const bf16* __restrict__ WcT2,
                                                 const bf16* __restrict__ zp,
                                                 const float* __restrict__ x,
                                                 float* __restrict__ out) {
    __shared__ bf16 lds_a[2][4096];      // 16 KB: A(k) double buffer, frag-major
    __shared__ bf16 bounce[4][32 * 64];  // 16 KB: per-wave gather-transpose buf

    int tid = threadIdx.x;
    int wave = tid >> 6;
    int lane = tid & 63;
    int l31 = lane & 31;
    int half = lane >> 5;
    int g8 = lane >> 3;        // group id 0..7 (row within gather inst)
    int l7 = lane & 7;         // lane-in-group (16B chunk of the row)
    int pbase = blockIdx.x * 128 + wave * 32;

    bf16* pb = bounce[wave];

    f32x16 acc[2];
#pragma unroll
    for (int mt = 0; mt < 2; mt++)
#pragma unroll
        for (int r = 0; r < 16; r++) acc[mt][r] = 0.f;

    // idx for gather-inst i of offset k: point = pbase + i*8 + g8
    auto ldidx4 = [&](int k, int i) -> int {
        int pp = pbase + i * 8 + g8;
        return (k < KEEP && pp < N_PTS) ? nidx[(size_t)k * N_PTS + pp] : -1;
    };
    auto gaddr = [&](int iv) -> const bf16* {
        return iv >= 0 ? f + (size_t)iv * HD + l7 * 8 : zp + l7 * 8;
    };
    auto gather4 = [&](GR& g, const int (&iv)[4]) {
#pragma unroll
        for (int i = 0; i < 4; i++)
            g.v[i] = *(const bf16x8*)gaddr(iv[i]);
    };
    // scatter gathered rows (lane-group layout) into bounce, XOR-swizzled:
    // chunk c of row pp lands at position (c ^ (pp&7)); here c=l7, pp&7=g8.
    auto dswrite = [&](const GR& g) {
#pragma unroll
        for (int i = 0; i < 4; i++) {
            int pp = i * 8 + g8;                       // row 0..31
            *(bf16x8*)&pb[pp * 64 + ((l7 ^ g8) * 8)] = g.v[i];
        }
    };
    // stage A(k): wave w covers frags 2w, 2w+1 (2 x 1KB coalesced wave-loads)
    auto stageIssue = [&](int k, bf16x8& s0, bf16x8& s1) {
        const bf16* wk = WbT + ((size_t)k << 12) + wave * 1024 + lane * 8;
        s0 = *(const bf16x8*)(wk);
        s1 = *(const bf16x8*)(wk + 512);
    };
    auto stageWrite = [&](int kb, const bf16x8& s0, const bf16x8& s1) {
        bf16* d = &lds_a[kb][wave * 1024 + lane * 8];
        *(bf16x8*)(d) = s0;
        *(bf16x8*)(d + 512) = s1;
    };
    auto mfma8_lds = [&](int kb) {
        const bf16* A = lds_a[kb];
#pragma unroll
        for (int ks = 0; ks < 4; ks++) {
            int ci = ks * 2 + half;
            bf16x8 fb = *(const bf16x8*)&pb[l31 * 64 + ((ci ^ (l31 & 7)) * 8)];
            bf16x8 a0 = *(const bf16x8*)&A[(ks * 2 + 0) * 512 + lane * 8];
            bf16x8 a1 = *(const bf16x8*)&A[(ks * 2 + 1) * 512 + lane * 8];
            acc[0] = __builtin_amdgcn_mfma_f32_32x32x16_bf16(a0, fb, acc[0], 0, 0, 0);
            acc[1] = __builtin_amdgcn_mfma_f32_32x32x16_bf16(a1, fb, acc[1], 0, 0, 0);
        }
    };
    // substep k: issue stage-loads A(k+1) + gather(k+2) + idx(k+6); compute k
    // from lds_a[k&1] + bounce; write bounce rows k+1 and lds_a[(k+1)&1];
    // lgkmcnt(0) + raw barrier.
    auto substep = [&](int k, GR& gfill, const GR& gwrite, int (&slot)[4]) {
        bf16x8 sA0, sA1;
        stageIssue(k + 1, sA0, sA1);                   // 2 loads (oldest)
        __builtin_amdgcn_sched_barrier(0);
        gather4(gfill, slot);                          // 4 loads
#pragma unroll
        for (int i = 0; i < 4; i++) slot[i] = ldidx4(k + 6, i);   // 4 loads
        __builtin_amdgcn_sched_barrier(0);
        mfma8_lds(k & 1);                              // ds_read + MFMA (lgkm counted)
        __builtin_amdgcn_sched_barrier(0);
        dswrite(gwrite);                               // vmcnt(14), counted
        stageWrite((k + 1) & 1, sA0, sA1);             // vmcnt(8), counted
        asm volatile("s_waitcnt lgkmcnt(0)" ::: "memory");
        __builtin_amdgcn_s_barrier();
        __builtin_amdgcn_sched_barrier(0);
    };

    // ---- prologue ----
    int s0[4], s1[4], s2[4], s3[4];   // rotating idx slots, depth-4
#pragma unroll
    for (int i = 0; i < 4; i++) s0[i] = ldidx4(2, i);
#pragma unroll
    for (int i = 0; i < 4; i++) s1[i] = ldidx4(3, i);
#pragma unroll
    for (int i = 0; i < 4; i++) s2[i] = ldidx4(4, i);
#pragma unroll
    for (int i = 0; i < 4; i++) s3[i] = ldidx4(5, i);
    GR ge, go;
    {
        int i0[4], i1[4];
#pragma unroll
        for (int i = 0; i < 4; i++) i0[i] = ldidx4(0, i);
#pragma unroll
        for (int i = 0; i < 4; i++) i1[i] = ldidx4(1, i);
        GR g0;
        gather4(g0, i0);        // rows k=0
        gather4(go, i1);        // rows k=1 (bounce-written at substep 0)
        bf16x8 sA0, sA1;
        stageIssue(0, sA0, sA1);
        dswrite(g0);            // bounce holds k=0
        stageWrite(0, sA0, sA1);
        asm volatile("s_waitcnt lgkmcnt(0)" ::: "memory");
        __builtin_amdgcn_s_barrier();
        __builtin_amdgcn_sched_barrier(0);
    }

    // ---- main loop: k = 0..61 ----
    // even substep: fill ge (rows k+2), write go (rows k+1); odd: swap.
    for (int j = 0; j < 15; j++) {
        int k = 4 * j;
        substep(k,     ge, go, s0);
        substep(k + 1, go, ge, s1);
        substep(k + 2, ge, go, s2);
        substep(k + 3, go, ge, s3);
    }
    substep(60, ge, go, s0);
    substep(61, go, ge, s1);
    // ---- tail: k = 62 (lds_a[0] staged at substep 61; bounce holds rows 62)
    mfma8_lds(0);

    // ---- epilogue: out[p][c] = x[p][c] + elu(acc)^T @ Wc ----
    // P-transpose through bounce (per-wave, in-order DS, no barrier), Wc
    // frags direct from global (L2-hot, coalesced 1KB reads).
#pragma unroll
    for (int mt = 0; mt < 2; mt++) {
#pragma unroll
        for (int q = 0; q < 4; q++) {
            bf16x4 v;
#pragma unroll
            for (int jj = 0; jj < 4; jj++)
                v[jj] = (bf16)elu_f(acc[mt][q * 4 + jj]);
            int chunk = mt * 4 + q;   // h = chunk*8 + 4*half + j
            *(bf16x4*)&pb[l31 * 64 + ((chunk ^ (l31 & 7)) * 8) + 4 * half] = v;
        }
    }
    bf16x8 pa[4];
#pragma unroll
    for (int ks = 0; ks < 4; ks++) {
        int ci = 2 * ks + half;
        pa[ks] = *(const bf16x8*)&pb[l31 * 64 + ((ci ^ (l31 & 7)) * 8)];
    }
#pragma unroll
    for (int ct = 0; ct < 4; ct++) {
        f32x16 o;
#pragma unroll
        for (int r = 0; r < 16; r++) o[r] = 0.f;
        int cc = ct * 32 + l31;
#pragma unroll
        for (int ks = 0; ks < 4; ks++) {
            bf16x8 bw = *(const bf16x8*)(WcT2 + ((ct * 4 + ks) << 9) + lane * 8);
            o = __builtin_amdgcn_mfma_f32_32x32x16_bf16(pa[ks], bw, o, 0, 0, 0);
        }
        int prow_base = pbase + 4 * half;
#pragma unroll
        for (int r = 0; r < 16; r++) {
            int prow = prow_base + (r & 3) + 8 * (r >> 2);
            if (prow < N_PTS) {
                size_t off = (size_t)prow * CD + cc;
                out[off] = x[off] + o[r];
            }
        }
    }
}

// ---------------------------------------------------------------------------
extern "C" void kernel_launch(void* const* d_in, const int* in_sizes, int n_in,
                              void* d_out, int out_size, void* d_ws, size_t ws_size,
                              hipStream_t stream) {
    const float* x  = (const float*)d_in[0];
    const float* y  = (const float*)d_in[1];
    const float* Wa = (const float*)d_in[2];
    const float* Wb = (const float*)d_in[3];
    const float* Wc = (const float*)d_in[4];
    const int* nidx = (const int*)d_in[5];
    float* out = (float*)d_out;

    char* ws = (char*)d_ws;
    bf16* f    = (bf16*)ws;                           // 200192*64*2 = 25,624,576 B
    bf16* WbT  = (bf16*)(ws + 25624576);              // 63*4096*2   =    516,096 B
    bf16* WcT2 = (bf16*)(ws + 25624576 + 516096);     // 8192*2      =     16,384 B
    bf16* WaT  = (bf16*)(ws + 25624576 + 516096 + 16384);   // 8192*2 = 16,384 B
    bf16* zp   = (bf16*)(ws + 25624576 + 516096 + 16384 + 16384);  // 128 B zeros

    k_prep<<<1073, 256, 0, stream>>>(Wb, Wc, Wa, WbT, WcT2, WaT, zp);
    k_stage1<<<1563, 256, 0, stream>>>(x, y, WaT, f);
    k_conv<<<1563, 256, 0, stream>>>(f, nidx, WbT, WcT2, zp, x, out);
}